// Round 13
// baseline (205.634 us; speedup 1.0000x reference)
//
#include <hip/hip_runtime.h>
#include <hip/hip_bf16.h>

#define NN 50000
#define NE 400000
#define IND 64
#define HID 128
#define H3 384
#define FDIM 960
#define NSEL 4096
#define EPSF 0.3f
#define SLOPEF 0.3f
#define NBK 196            // ceil(NN/256) dst-buckets per relation
#define BCAP 4096          // fixed bucket capacity (mean 2048, sigma 45)
#define EPB 4096           // edges per block in fill
#define NOEDGE 0xFFFFFFFFu
#define NBF 98             // blocks per relation in fill = ceil(NE/EPB)

typedef __attribute__((ext_vector_type(8))) short bfrag;   // 8 bf16 (4 VGPR)
typedef __attribute__((ext_vector_type(4))) float f4;
typedef __attribute__((ext_vector_type(8))) unsigned short us8;

__device__ __forceinline__ float leaky1(float v){ return v>=0.f? v : SLOPEF*v; }
__device__ __forceinline__ float b2f(unsigned short u){
  return __uint_as_float(((unsigned)u)<<16);
}
__device__ __forceinline__ unsigned short f2b(float v){
  __hip_bfloat16 b = __float2bfloat16(v);
  return *(unsigned short*)&b;
}

// ================= kA: bucketed fill (blocks 0..293)  UNION  weight-prep/h-cast =================
__global__ __launch_bounds__(256) void k_fill_prep(
    const int* __restrict__ s0,const int* __restrict__ d0,
    const int* __restrict__ s1,const int* __restrict__ d1,
    const int* __restrict__ s2,const int* __restrict__ d2,
    int* __restrict__ bcnt, unsigned int* __restrict__ pairbuf,
    const float* __restrict__ t1w,
    const float* __restrict__ hw1_0, const float* __restrict__ hw1_1, const float* __restrict__ hw1_2,
    const float* __restrict__ hw2_0, const float* __restrict__ hw2_1, const float* __restrict__ hw2_2,
    const float* __restrict__ t2w, const float* __restrict__ h,
    unsigned short* __restrict__ wt1, unsigned short* __restrict__ w1t,
    unsigned short* __restrict__ w2t, unsigned short* __restrict__ wt2,
    unsigned short* __restrict__ hb)
{
  __shared__ __align__(16) unsigned int lbuf[EPB];   // 16 KB
  __shared__ int hist[256];
  __shared__ int lbase[256];
  __shared__ int lcur[256];
  __shared__ int gbase[NBK];
  __shared__ int wsum[4];
  const int t = threadIdx.x;

  if (blockIdx.x < 3*NBF){
    const int r = blockIdx.x / NBF;
    const int bx = blockIdx.x - r*NBF;
    const int* S = (r==0)?s0:((r==1)?s1:s2);
    const int* D = (r==0)?d0:((r==1)?d1:d2);
    const int e0 = bx*EPB;
    hist[t] = 0; lcur[t] = 0;
    __syncthreads();
    unsigned int pv[16];
    #pragma unroll
    for (int j=0;j<4;j++){
      int e = e0 + (j*256 + t)*4;
      if (e < NE){
        int4 sv = *(const int4*)&S[e];
        int4 dv = *(const int4*)&D[e];
        pv[j*4+0] = ((unsigned)dv.x<<16)|(unsigned)sv.x;
        pv[j*4+1] = ((unsigned)dv.y<<16)|(unsigned)sv.y;
        pv[j*4+2] = ((unsigned)dv.z<<16)|(unsigned)sv.z;
        pv[j*4+3] = ((unsigned)dv.w<<16)|(unsigned)sv.w;
      } else {
        pv[j*4+0]=NOEDGE; pv[j*4+1]=NOEDGE; pv[j*4+2]=NOEDGE; pv[j*4+3]=NOEDGE;
      }
    }
    #pragma unroll
    for (int i=0;i<16;i++){
      if (pv[i] != NOEDGE) atomicAdd(&hist[pv[i]>>24], 1);
    }
    __syncthreads();
    {
      int hv = hist[t];
      int lane = t & 63, wid = t >> 6;
      int x = hv;
      #pragma unroll
      for (int d=1; d<64; d<<=1){ int y=__shfl_up(x,(unsigned)d); if(lane>=d) x+=y; }
      if (lane==63) wsum[wid]=x;
      __syncthreads();
      int wpre = 0;
      if (wid>0) wpre += wsum[0];
      if (wid>1) wpre += wsum[1];
      if (wid>2) wpre += wsum[2];
      lbase[t] = wpre + x - hv;
      if (t < NBK){
        int hh = hist[t];
        gbase[t] = (hh>0) ? atomicAdd(&bcnt[r*NBK+t], hh) : 0;
      }
    }
    __syncthreads();
    #pragma unroll
    for (int i=0;i<16;i++){
      if (pv[i] != NOEDGE){
        int b = (int)(pv[i] >> 24);
        int pos = lbase[b] + atomicAdd(&lcur[b], 1);
        lbuf[pos] = pv[i];
      }
    }
    __syncthreads();
    int tot = min(NE - e0, EPB);
    for (int idx = t; idx < tot; idx += 256){
      unsigned int v = lbuf[idx];
      int b = (int)(v >> 24);
      pairbuf[((size_t)(r*NBK + b))*BCAP + gbase[b] + (idx - lbase[b])] = v;
    }
  } else {
    int g = (blockIdx.x - 3*NBF)*256 + t;
    if (g < 8192){
      wt1[g] = f2b(t1w[g]);
    } else if (g < 57344){
      int e = g - 8192;
      int r = e / 16384, q = e - r*16384;
      int n = q >> 7, k = q & 127;
      const float* W = (r==0)?hw1_0:((r==1)?hw1_1:hw1_2);
      w1t[e] = f2b(W[k*HID + n]);
    } else if (g < 204800){
      int e = g - 57344;
      int r = e / 49152, q = e - r*49152;
      int n = q / H3, k = q - n*H3;
      const float* W = (r==0)?hw2_0:((r==1)?hw2_1:hw2_2);
      w2t[e] = f2b(W[k*HID + n]);
    } else if (g < 266240){
      int e = g - 204800;
      wt2[e] = f2b(t2w[e]);
    } else if (g < 666240){
      int q = g - 266240;
      const float4 a = ((const float4*)h)[q*2];
      const float4 b = ((const float4*)h)[q*2+1];
      us8 o;
      o[0]=f2b(a.x); o[1]=f2b(a.y); o[2]=f2b(a.z); o[3]=f2b(a.w);
      o[4]=f2b(b.x); o[5]=f2b(b.y); o[6]=f2b(b.z); o[7]=f2b(b.w);
      *(us8*)&hb[q*8] = o;
    }
  }
}

// ============ kB: bsort+off+dnv (0..587)  UNION  t1 MFMA + fused scores1 ============
__global__ __launch_bounds__(256) void k_sort_t1(
    const unsigned int* __restrict__ pairbuf, const int* __restrict__ bcnt,
    int* __restrict__ off, float* __restrict__ dnv, unsigned short* __restrict__ csrc,
    const unsigned short* __restrict__ Ab, const unsigned short* __restrict__ W,
    const float* __restrict__ bias, unsigned short* __restrict__ Cb,
    const float* __restrict__ g1w0, const float* __restrict__ g1w1, const float* __restrict__ g1w2,
    float* __restrict__ sd1, float* __restrict__ ss1)
{
  __shared__ __align__(16) char smem[29184];
  const int t = threadIdx.x;

  if (blockIdx.x < 3*NBK){
    // ---- bucket sort + off/dnv ----
    unsigned short* lout = (unsigned short*)smem;            // 8192 B
    int* hist = (int*)(smem + 8192);
    int* excl = (int*)(smem + 9216);
    int* cur  = (int*)(smem + 10240);
    int* red  = (int*)(smem + 11264);
    int* wsum = (int*)(smem + 12288);
    const int r = blockIdx.x / NBK;
    const int b = blockIdx.x - r*NBK;
    const int nb0 = b << 8;
    red[t] = (t < b) ? bcnt[r*NBK + t] : 0;
    hist[t] = 0; cur[t] = 0;
    __syncthreads();
    #pragma unroll
    for (int sdv=128; sdv>0; sdv>>=1){
      if (t < sdv) red[t] += red[t+sdv];
      __syncthreads();
    }
    const int bbase = red[0];
    const int cnt = bcnt[r*NBK + b];
    const unsigned int* pb = pairbuf + ((size_t)(r*NBK + b))*BCAP;
    unsigned int pv[16];
    #pragma unroll
    for (int j=0;j<16;j++){
      int e = j*256 + t;
      pv[j] = (e < cnt) ? pb[e] : NOEDGE;
      if (pv[j] != NOEDGE) atomicAdd(&hist[(int)(pv[j]>>16) - nb0], 1);
    }
    __syncthreads();
    {
      int hv = hist[t];
      int lane = t & 63, wid = t >> 6;
      int x = hv;
      #pragma unroll
      for (int d=1; d<64; d<<=1){ int y=__shfl_up(x,(unsigned)d); if(lane>=d) x+=y; }
      if (lane==63) wsum[wid]=x;
      __syncthreads();
      int wpre = 0;
      if (wid>0) wpre += wsum[0];
      if (wid>1) wpre += wsum[1];
      if (wid>2) wpre += wsum[2];
      excl[t] = wpre + x - hv;
    }
    __syncthreads();
    int nidx = nb0 + t;
    if (nidx < NN){
      off[r*(NN+1) + nidx] = bbase + excl[t];
      int g = hist[t];
      dnv[r*NN + nidx] = (g>0) ? rsqrtf((float)g) : 0.f;
    }
    if (b == NBK-1 && t == 0) off[r*(NN+1) + NN] = bbase + cnt;
    #pragma unroll
    for (int j=0;j<16;j++){
      if (pv[j] != NOEDGE){
        int pn = (int)(pv[j] >> 16) - nb0;
        int slot = atomicAdd(&cur[pn], 1);
        lout[excl[pn] + slot] = (unsigned short)(pv[j] & 0xffffu);
      }
    }
    __syncthreads();
    unsigned short* op = csrc + (size_t)r*NE + bbase;
    for (int idx = t; idx < cnt; idx += 256) op[idx] = lout[idx];
  } else {
    // ---- t1 MFMA + fused layer-1 gate scores ----
    short (*As)[72] = (short(*)[72])smem;                    // 9216 B
    short (*Bs)[72] = (short(*)[72])(smem + 9216);           // 18432 B
    float* sc = (float*)(smem + 27648);                      // 64*6 = 1536 B
    const int bm = (blockIdx.x - 3*NBK)*64;
    for (int q = t; q < 64*8; q += 256){
      int row = q >> 3, c8 = q & 7;
      int grow = bm + row; grow = (grow < NN) ? grow : (NN-1);
      *(us8*)&As[row][c8*8] = *(const us8*)&Ab[(size_t)grow*IND + c8*8];
    }
    for (int q = t; q < 128*8; q += 256){
      int n = q >> 3, c8 = q & 7;
      *(us8*)&Bs[n][c8*8] = *(const us8*)&W[n*IND + c8*8];
    }
    for (int q = t; q < 384; q += 256) sc[q] = 0.f;
    __syncthreads();
    const int wid = t >> 6, lane = t & 63;
    const int wrow = (wid & 1)*32, wcol = (wid >> 1)*64;
    const int fr = lane & 15, fq = lane >> 4;
    f4 acc[2][4];
    #pragma unroll
    for (int mi=0;mi<2;mi++)
      #pragma unroll
      for (int ni=0;ni<4;ni++) acc[mi][ni] = (f4){0.f,0.f,0.f,0.f};
    #pragma unroll
    for (int ks=0; ks<2; ks++){
      int kb = ks*32 + fq*8;
      bfrag a[2], b[4];
      #pragma unroll
      for (int mi=0;mi<2;mi++) a[mi] = *(const bfrag*)&As[wrow + mi*16 + fr][kb];
      #pragma unroll
      for (int ni=0;ni<4;ni++) b[ni] = *(const bfrag*)&Bs[wcol + ni*16 + fr][kb];
      #pragma unroll
      for (int mi=0;mi<2;mi++)
        #pragma unroll
        for (int ni=0;ni<4;ni++)
          acc[mi][ni] = __builtin_amdgcn_mfma_f32_16x16x32_bf16(a[mi], b[ni], acc[mi][ni], 0, 0, 0);
    }
    #pragma unroll
    for (int mi=0;mi<2;mi++){
      #pragma unroll
      for (int j=0;j<4;j++){
        int rowloc = wrow + mi*16 + fq*4 + j;
        int row = bm + rowloc;
        bool ok = row < NN;
        float l6[6] = {0,0,0,0,0,0};
        #pragma unroll
        for (int ni=0;ni<4;ni++){
          int col = wcol + ni*16 + fr;
          float v = leaky1(acc[mi][ni][j] + bias[col]);
          if (ok) Cb[(size_t)row*HID + col] = f2b(v);
          l6[0] = fmaf(v, g1w0[col],     l6[0]);
          l6[1] = fmaf(v, g1w0[HID+col], l6[1]);
          l6[2] = fmaf(v, g1w1[col],     l6[2]);
          l6[3] = fmaf(v, g1w1[HID+col], l6[3]);
          l6[4] = fmaf(v, g1w2[col],     l6[4]);
          l6[5] = fmaf(v, g1w2[HID+col], l6[5]);
        }
        #pragma unroll
        for (int k=0;k<6;k++){
          l6[k] += __shfl_xor(l6[k], 1);
          l6[k] += __shfl_xor(l6[k], 2);
          l6[k] += __shfl_xor(l6[k], 4);
          l6[k] += __shfl_xor(l6[k], 8);
        }
        if (fr == 0){
          #pragma unroll
          for (int k=0;k<6;k++) atomicAdd(&sc[rowloc*6 + k], l6[k]);
        }
      }
    }
    __syncthreads();
    if (t < 64){
      int row = bm + t;
      if (row < NN){
        sd1[0*NN+row] = sc[t*6+0]; ss1[0*NN+row] = sc[t*6+1];
        sd1[1*NN+row] = sc[t*6+2]; ss1[1*NN+row] = sc[t*6+3];
        sd1[2*NN+row] = sc[t*6+4]; ss1[2*NN+row] = sc[t*6+5];
      }
    }
  }
}

// ====== hw1 MFMA, 3 relation-chunks sequential per block + fused scores2 ======
__global__ __launch_bounds__(256) void k_mfma128s(
    const unsigned short* __restrict__ Abf, const unsigned short* __restrict__ Wt,
    const float* __restrict__ g2w0, const float* __restrict__ g2w1, const float* __restrict__ g2w2,
    unsigned short* __restrict__ Cb, float* __restrict__ sd2, float* __restrict__ ss2, int M)
{
  __shared__ short As[64][136];
  __shared__ short Bs[128][136];
  __shared__ float sc[384];
  const int tid = threadIdx.x;
  const int bm = blockIdx.x*64;
  const int wid = tid >> 6, lane = tid & 63;
  const int wrow = (wid & 1)*32, wcol = (wid >> 1)*64;
  const int fr = lane & 15, fq = lane >> 4;

  for (int q = tid; q < 384; q += 256) sc[q] = 0.f;

  for (int rc=0; rc<3; rc++){
    const unsigned short* Ar = Abf + (size_t)rc*M*HID;
    const unsigned short* W  = Wt + (size_t)rc*HID*HID;
    for (int q = tid; q < 64*16; q += 256){
      int row = q >> 4, c8 = q & 15;
      int grow = bm + row; grow = (grow < M) ? grow : (M-1);
      *(us8*)&As[row][c8*8] = *(const us8*)&Ar[(size_t)grow*HID + c8*8];
    }
    for (int q = tid; q < 128*16; q += 256){
      int n = q >> 4, c8 = q & 15;
      *(us8*)&Bs[n][c8*8] = *(const us8*)&W[n*HID + c8*8];
    }
    __syncthreads();

    f4 acc[2][4];
    #pragma unroll
    for (int mi=0;mi<2;mi++)
      #pragma unroll
      for (int ni=0;ni<4;ni++) acc[mi][ni] = (f4){0.f,0.f,0.f,0.f};
    #pragma unroll
    for (int ks=0; ks<4; ks++){
      int kb = ks*32 + fq*8;
      bfrag a[2], b[4];
      #pragma unroll
      for (int mi=0;mi<2;mi++) a[mi] = *(const bfrag*)&As[wrow + mi*16 + fr][kb];
      #pragma unroll
      for (int ni=0;ni<4;ni++) b[ni] = *(const bfrag*)&Bs[wcol + ni*16 + fr][kb];
      #pragma unroll
      for (int mi=0;mi<2;mi++)
        #pragma unroll
        for (int ni=0;ni<4;ni++)
          acc[mi][ni] = __builtin_amdgcn_mfma_f32_16x16x32_bf16(a[mi], b[ni], acc[mi][ni], 0, 0, 0);
    }

    const int coff = rc*HID;
    #pragma unroll
    for (int mi=0;mi<2;mi++){
      #pragma unroll
      for (int j=0;j<4;j++){
        int rowloc = wrow + mi*16 + fq*4 + j;
        int row = bm + rowloc;
        bool ok = row < M;
        float l6[6] = {0,0,0,0,0,0};
        #pragma unroll
        for (int ni=0;ni<4;ni++){
          int col = wcol + ni*16 + fr;
          float v = leaky1(acc[mi][ni][j]);
          if (ok) Cb[(size_t)row*H3 + coff + col] = f2b(v);
          int gc = coff + col;
          l6[0] = fmaf(v, g2w0[gc],    l6[0]);
          l6[1] = fmaf(v, g2w0[H3+gc], l6[1]);
          l6[2] = fmaf(v, g2w1[gc],    l6[2]);
          l6[3] = fmaf(v, g2w1[H3+gc], l6[3]);
          l6[4] = fmaf(v, g2w2[gc],    l6[4]);
          l6[5] = fmaf(v, g2w2[H3+gc], l6[5]);
        }
        #pragma unroll
        for (int k=0;k<6;k++){
          l6[k] += __shfl_xor(l6[k], 1);
          l6[k] += __shfl_xor(l6[k], 2);
          l6[k] += __shfl_xor(l6[k], 4);
          l6[k] += __shfl_xor(l6[k], 8);
        }
        if (fr == 0){
          #pragma unroll
          for (int k=0;k<6;k++) atomicAdd(&sc[rowloc*6 + k], l6[k]);
        }
      }
    }
    __syncthreads();
  }

  if (tid < 64){
    int row = bm + tid;
    if (row < M){
      sd2[0*NN+row] = sc[tid*6+0]; ss2[0*NN+row] = sc[tid*6+1];
      sd2[1*NN+row] = sc[tid*6+2]; ss2[1*NN+row] = sc[tid*6+3];
      sd2[2*NN+row] = sc[tid*6+4]; ss2[2*NN+row] = sc[tid*6+5];
    }
  }
}

// ================= kH: hw2 MFMA (0..383)  UNION  nf fill =================
__global__ __launch_bounds__(256) void k_hw2_nf(
    const unsigned short* __restrict__ Abf, const unsigned short* __restrict__ Wt,
    const unsigned short* __restrict__ hb, const unsigned short* __restrict__ raw1b,
    const unsigned short* __restrict__ raw2b, const int* __restrict__ nodes,
    unsigned short* __restrict__ nfb)
{
  __shared__ __align__(16) char smem[23040];
  const int t = threadIdx.x;
  if (blockIdx.x < 3*128){
    short (*As)[72] = (short(*)[72])smem;
    short (*Bs)[72] = (short(*)[72])(smem + 4608);
    const int r = blockIdx.x / 128;
    const int bm = (blockIdx.x - r*128)*32;
    const unsigned short* Ar = Abf + (size_t)r*NSEL*H3;
    const unsigned short* W  = Wt + (size_t)r*HID*H3;
    const int wid = t >> 6, lane = t & 63;
    const int fr = lane & 15, fq = lane >> 4;
    f4 acc[2][2];
    #pragma unroll
    for (int mi=0;mi<2;mi++)
      #pragma unroll
      for (int ni=0;ni<2;ni++) acc[mi][ni] = (f4){0.f,0.f,0.f,0.f};
    for (int kc=0; kc<6; kc++){
      for (int q = t; q < 32*8; q += 256){
        int row = q >> 3, c8 = q & 7;
        *(us8*)&As[row][c8*8] = *(const us8*)&Ar[(size_t)(bm+row)*H3 + kc*64 + c8*8];
      }
      for (int q = t; q < 128*8; q += 256){
        int n = q >> 3, c8 = q & 7;
        *(us8*)&Bs[n][c8*8] = *(const us8*)&W[(size_t)n*H3 + kc*64 + c8*8];
      }
      __syncthreads();
      #pragma unroll
      for (int ks=0; ks<2; ks++){
        int kb = ks*32 + fq*8;
        bfrag a[2], b[2];
        #pragma unroll
        for (int mi=0;mi<2;mi++) a[mi] = *(const bfrag*)&As[mi*16 + fr][kb];
        #pragma unroll
        for (int ni=0;ni<2;ni++) b[ni] = *(const bfrag*)&Bs[wid*32 + ni*16 + fr][kb];
        #pragma unroll
        for (int mi=0;mi<2;mi++)
          #pragma unroll
          for (int ni=0;ni<2;ni++)
            acc[mi][ni] = __builtin_amdgcn_mfma_f32_16x16x32_bf16(a[mi], b[ni], acc[mi][ni], 0, 0, 0);
      }
      __syncthreads();
    }
    #pragma unroll
    for (int mi=0;mi<2;mi++){
      int row0 = bm + mi*16 + fq*4;
      #pragma unroll
      for (int j=0;j<4;j++){
        int i = row0 + j;
        #pragma unroll
        for (int ni=0;ni<2;ni++){
          int col = wid*32 + ni*16 + fr;
          nfb[(size_t)i*FDIM + r*HID + col] = f2b(leaky1(acc[mi][ni][j]));
        }
      }
    }
  } else {
    int g = (blockIdx.x - 3*128)*256 + t;
    if (g < NSEL*72){
      int i = g/72, c = g - i*72;
      int n = nodes[i];
      us8 v; int col;
      if (c < 8)       { v = *(const us8*)&hb[(size_t)n*IND + c*8];           col = 384 + c*8; }
      else if (c < 24) { int q=c-8;  v = *(const us8*)&raw1b[(size_t)n*HID + q*8]; col = 448 + q*8; }
      else             { int q=c-24; v = *(const us8*)&raw2b[(size_t)n*H3  + q*8]; col = 576 + q*8; }
      *(us8*)&nfb[(size_t)i*FDIM + col] = v;
    }
  }
}

// ================= kT2F: t2 MFMA (K=960) + fused bias/leaky/t3 epilogue =================
__global__ __launch_bounds__(256) void k_t2_final(
    const unsigned short* __restrict__ Abf, const unsigned short* __restrict__ W,
    const float* __restrict__ t2b, const float* __restrict__ t3w,
    const float* __restrict__ t3b, float* __restrict__ outp)
{
  __shared__ __align__(16) char smem[13824];
  short (*As)[72] = (short(*)[72])smem;
  short (*Bs)[72] = (short(*)[72])(smem + 4608);
  float (*sb)[64] = (float(*)[64])smem;
  const int t = threadIdx.x;
  const int bm = blockIdx.x*32;
  const int wid = t >> 6, lane = t & 63;
  const int fr = lane & 15, fq = lane >> 4;
  f4 acc[2];
  acc[0] = (f4){0.f,0.f,0.f,0.f};
  acc[1] = (f4){0.f,0.f,0.f,0.f};

  for (int kc=0; kc<15; kc++){
    for (int q = t; q < 32*8; q += 256){
      int row = q >> 3, c8 = q & 7;
      *(us8*)&As[row][c8*8] = *(const us8*)&Abf[(size_t)(bm+row)*FDIM + kc*64 + c8*8];
    }
    for (int q = t; q < 64*8; q += 256){
      int n = q >> 3, c8 = q & 7;
      *(us8*)&Bs[n][c8*8] = *(const us8*)&W[(size_t)n*FDIM + kc*64 + c8*8];
    }
    __syncthreads();
    #pragma unroll
    for (int ks=0; ks<2; ks++){
      int kb = ks*32 + fq*8;
      bfrag a[2], b;
      a[0] = *(const bfrag*)&As[fr][kb];
      a[1] = *(const bfrag*)&As[16 + fr][kb];
      b = *(const bfrag*)&Bs[wid*16 + fr][kb];
      acc[0] = __builtin_amdgcn_mfma_f32_16x16x32_bf16(a[0], b, acc[0], 0, 0, 0);
      acc[1] = __builtin_amdgcn_mfma_f32_16x16x32_bf16(a[1], b, acc[1], 0, 0, 0);
    }
    __syncthreads();
  }

  #pragma unroll
  for (int mi=0;mi<2;mi++){
    int rloc = mi*16 + fq*4;
    #pragma unroll
    for (int j=0;j<4;j++){
      sb[rloc+j][wid*16 + fr] = acc[mi][j];
    }
  }
  __syncthreads();
  for (int rr = wid*8; rr < wid*8+8; rr++){
    float v = leaky1(sb[rr][lane] + t2b[lane]);
    float a0 = v*t3w[lane], a1 = v*t3w[64+lane];
    #pragma unroll
    for (int sft=32;sft>0;sft>>=1){
      a0 += __shfl_down(a0,(unsigned)sft);
      a1 += __shfl_down(a1,(unsigned)sft);
    }
    if (lane==0){
      int w = bm + rr;
      outp[2*w+0] = a0 + t3b[0];
      outp[2*w+1] = a1 + t3b[1];
    }
  }
}

// ---------- layer-1 aggregation: group(16)-per-node, 3 rels fused, 1-ahead pipeline ----------
__global__ __launch_bounds__(256) void k_gather_f3z(
    const unsigned short* __restrict__ Xb,
    const int* __restrict__ off, const unsigned short* __restrict__ csrc,
    const float* __restrict__ sd, const float* __restrict__ ss,
    const float* __restrict__ dnv,
    const float* __restrict__ gb0, const float* __restrict__ gb1, const float* __restrict__ gb2,
    unsigned short* __restrict__ outp){
  const int tid = threadIdx.x;
  const int lane = tid & 63;
  const int wg = lane >> 4;
  const int p  = lane & 15;
  const int n = blockIdx.x*16 + (tid >> 4);
  us8 rv = *(const us8*)&Xb[(size_t)n*HID + p*8];
  int p0a[3], p1a[3];
  #pragma unroll
  for (int r=0;r<3;r++){
    p0a[r] = off[r*(NN+1) + n];
    p1a[r] = off[r*(NN+1) + n + 1];
  }
  float resid[8];
  #pragma unroll
  for (int i=0;i<8;i++) resid[i] = EPSF * b2f(rv[i]);

  for (int r=0;r<3;r++){
    const unsigned short* csr = csrc + (size_t)r*NE;
    const float* ssr = ss + r*NN;
    const float* dnr = dnv + r*NN;
    float gbv = ((r==0)?gb0:((r==1)?gb1:gb2))[0];
    float sd_n = sd[r*NN + n], dn_n = dnr[n];
    float acc[8];
    #pragma unroll
    for (int i=0;i<8;i++) acc[i] = resid[i];
    int p0 = p0a[r], p1 = p1a[r];
    for (int pc=p0; pc<p1; pc+=16){
      int m = min(16, p1-pc);
      int s = 0; float c = 0.f;
      if (p < m){
        s = csr[pc+p];
        c = tanhf(sd_n + ssr[s] + gbv) * dn_n * dnr[s];
      }
      int   sj = __shfl(s, wg*16);
      float cj = __shfl(c, wg*16);
      us8 v = *(const us8*)&Xb[(size_t)sj*HID + p*8];
      for (int j=1;j<=m;j++){
        us8 vn; float cn = 0.f;
        if (j < m){
          int sn = __shfl(s, wg*16+j);
          cn = __shfl(c, wg*16+j);
          vn = *(const us8*)&Xb[(size_t)sn*HID + p*8];
        }
        #pragma unroll
        for (int i=0;i<8;i++) acc[i] = fmaf(cj, b2f(v[i]), acc[i]);
        v = vn; cj = cn;
      }
    }
    us8 o;
    #pragma unroll
    for (int i=0;i<8;i++) o[i] = f2b(acc[i]);
    *(us8*)&outp[((size_t)r*NN + n)*HID + p*8] = o;
  }
}

// ---------- layer-2 selected aggregation: group-per-node, D=384, 1-ahead pipeline ----------
__global__ __launch_bounds__(256) void k_gather_sel3w2(const unsigned short* __restrict__ Xb,
    const int* __restrict__ nodes,
    const int* __restrict__ off, const unsigned short* __restrict__ csrc,
    const float* __restrict__ sd, const float* __restrict__ ss,
    const float* __restrict__ dnv,
    const float* __restrict__ gb0, const float* __restrict__ gb1, const float* __restrict__ gb2,
    unsigned short* __restrict__ outp){
  const int tid = threadIdx.x;
  const int lane = tid & 63;
  const int wg = lane >> 4;
  const int p  = lane & 15;
  const int i = blockIdx.x*16 + (tid >> 4);
  const int r = blockIdx.y;
  const int n = nodes[i];
  const int* offr = off + r*(NN+1);
  const unsigned short* csr = csrc + (size_t)r*NE;
  const float* ssr = ss + r*NN;
  const float* dnr = dnv + r*NN;
  float gbv = ((r==0)?gb0:((r==1)?gb1:gb2))[0];
  float sd_n = sd[r*NN + n], dn_n = dnr[n];
  float acc[3][8];
  #pragma unroll
  for (int cc=0;cc<3;cc++)
    #pragma unroll
    for (int q=0;q<8;q++) acc[cc][q]=0.f;
  int p0 = offr[n], p1 = offr[n+1];
  for (int pc=p0; pc<p1; pc+=16){
    int m = min(16, p1-pc);
    int s = 0; float c = 0.f;
    if (p < m){
      s = csr[pc+p];
      c = tanhf(sd_n + ssr[s] + gbv) * dn_n * dnr[s];
    }
    int   sj = __shfl(s, wg*16);
    float cj = __shfl(c, wg*16);
    const unsigned short* row = &Xb[(size_t)sj*H3];
    us8 v0 = *(const us8*)&row[0*HID + p*8];
    us8 v1 = *(const us8*)&row[1*HID + p*8];
    us8 v2 = *(const us8*)&row[2*HID + p*8];
    for (int j=1;j<=m;j++){
      us8 n0, n1, n2; float cn = 0.f;
      if (j < m){
        int sn = __shfl(s, wg*16+j);
        cn = __shfl(c, wg*16+j);
        const unsigned short* rw = &Xb[(size_t)sn*H3];
        n0 = *(const us8*)&rw[0*HID + p*8];
        n1 = *(const us8*)&rw[1*HID + p*8];
        n2 = *(const us8*)&rw[2*HID + p*8];
      }
      #pragma unroll
      for (int q=0;q<8;q++){
        acc[0][q] = fmaf(cj, b2f(v0[q]), acc[0][q]);
        acc[1][q] = fmaf(cj, b2f(v1[q]), acc[1][q]);
        acc[2][q] = fmaf(cj, b2f(v2[q]), acc[2][q]);
      }
      v0 = n0; v1 = n1; v2 = n2; cj = cn;
    }
  }
  const unsigned short* xrow = &Xb[(size_t)n*H3];
  unsigned short* orow = &outp[((size_t)r*NSEL + i)*H3];
  #pragma unroll
  for (int cc=0;cc<3;cc++){
    us8 v = *(const us8*)&xrow[cc*HID + p*8];
    us8 o;
    #pragma unroll
    for (int q=0;q<8;q++) o[q] = f2b(fmaf(EPSF, b2f(v[q]), acc[cc][q]));
    *(us8*)&orow[cc*HID + p*8] = o;
  }
}

extern "C" void kernel_launch(void* const* d_in, const int* in_sizes, int n_in,
                              void* d_out, int out_size, void* d_ws, size_t ws_size,
                              hipStream_t stream){
  if (n_in < 32) return;
  const float* h = (const float*)d_in[0];
  const int* src[3] = {(const int*)d_in[1], (const int*)d_in[3], (const int*)d_in[5]};
  const int* dst[3] = {(const int*)d_in[2], (const int*)d_in[4], (const int*)d_in[6]};
  const int* nodes = (const int*)d_in[7];
  const float* t1w = (const float*)d_in[8];
  const float* t1b = (const float*)d_in[9];

  bool dictOrder = (in_sizes[12] == 768);
  const float *g1w[3],*g1b[3],*g2w[3],*g2b[3],*hw1[3],*hw2[3];
  for (int r=0;r<3;r++){
    if (dictOrder){
      int base = 10 + r*6;
      g1w[r]=(const float*)d_in[base+0]; g1b[r]=(const float*)d_in[base+1];
      g2w[r]=(const float*)d_in[base+2]; g2b[r]=(const float*)d_in[base+3];
      hw1[r]=(const float*)d_in[base+4]; hw2[r]=(const float*)d_in[base+5];
    } else {
      g1w[r]=(const float*)d_in[10+2*r]; g1b[r]=(const float*)d_in[11+2*r];
      g2w[r]=(const float*)d_in[16+2*r]; g2b[r]=(const float*)d_in[17+2*r];
      hw1[r]=(const float*)d_in[22+r];   hw2[r]=(const float*)d_in[25+r];
    }
  }
  const float* t2w = (const float*)d_in[28];
  const float* t2b = (const float*)d_in[29];
  const float* t3w = (const float*)d_in[30];
  const float* t3b = (const float*)d_in[31];
  float* outp = (float*)d_out;

  // workspace carve (~115 MB)
  char* w = (char*)d_ws;
  auto carve = [&](size_t bytes)->void*{
    void* p = (void*)w;
    w += ((bytes + 255) & ~size_t(255));
    return p;
  };
  int*   bcnt = (int*)  carve((size_t)1024*4);
  int*   off  = (int*)  carve((size_t)3*(NN+1)*4);
  float* dnv  = (float*)carve((size_t)3*NN*4);
  unsigned short* csrc = (unsigned short*)carve((size_t)3*NE*2);
  float* sd1  = (float*)carve((size_t)3*NN*4);
  float* ss1  = (float*)carve((size_t)3*NN*4);
  float* sd2  = (float*)carve((size_t)3*NN*4);
  float* ss2  = (float*)carve((size_t)3*NN*4);
  unsigned short* wt1 = (unsigned short*)carve((size_t)HID*IND*2);
  unsigned short* w1t = (unsigned short*)carve((size_t)3*HID*HID*2);
  unsigned short* w2t = (unsigned short*)carve((size_t)3*HID*H3*2);
  unsigned short* wt2 = (unsigned short*)carve((size_t)64*FDIM*2);
  unsigned short* hb  = (unsigned short*)carve((size_t)NN*IND*2);
  unsigned short* raw1b = (unsigned short*)carve((size_t)NN*HID*2);
  unsigned short* raw2b = (unsigned short*)carve((size_t)NN*H3*2);
  // union region (38.4MB): pairbuf u32 [3*NBK*BCAP] | pre1b [3][NN][HID] | pre2b [3][NSEL][H3]
  size_t ubytes = (size_t)3*NN*HID*2;
  float* ureg = (float*)carve(ubytes);
  unsigned int* pairbuf = (unsigned int*)ureg;
  unsigned short* pre1b = (unsigned short*)ureg;
  unsigned short* pre2b = (unsigned short*)ureg;
  unsigned short* nfb = (unsigned short*)carve((size_t)NSEL*FDIM*2);

  hipMemsetAsync(bcnt, 0, (size_t)1024*4, stream);
  // kA: fill + weight-prep
  k_fill_prep<<<3*NBF + 2603, 256, 0, stream>>>(
      src[0],dst[0],src[1],dst[1],src[2],dst[2], bcnt, pairbuf,
      t1w, hw1[0], hw1[1], hw1[2], hw2[0], hw2[1], hw2[2], t2w, h,
      wt1, w1t, w2t, wt2, hb);
  // kB: bucket-sort/off/dnv + t1 MFMA with fused scores1
  k_sort_t1<<<3*NBK + (NN+63)/64, 256, 0, stream>>>(
      pairbuf, bcnt, off, dnv, csrc, hb, wt1, t1b, raw1b,
      g1w[0], g1w[1], g1w[2], sd1, ss1);

  k_gather_f3z<<<NN/16, 256, 0, stream>>>(raw1b, off, csrc,
      sd1, ss1, dnv, g1b[0], g1b[1], g1b[2], pre1b);

  // hw1 MFMA (3 chunks/block) with fused scores2
  k_mfma128s<<<(NN+63)/64, 256, 0, stream>>>(pre1b, w1t,
      g2w[0], g2w[1], g2w[2], raw2b, sd2, ss2, NN);

  k_gather_sel3w2<<<dim3(NSEL/16, 3), 256, 0, stream>>>(raw2b, nodes, off, csrc,
      sd2, ss2, dnv, g2b[0], g2b[1], g2b[2], pre2b);

  // kH: hw2 MFMA + nf fill
  k_hw2_nf<<<3*128 + (NSEL*72+255)/256, 256, 0, stream>>>(
      pre2b, w2t, hb, raw1b, raw2b, nodes, nfb);

  // kT2F: t2 MFMA with fused bias/leaky/t3 epilogue
  k_t2_final<<<NSEL/32, 256, 0, stream>>>(nfb, wt2, t2b, t3w, t3b, outp);
}

// Round 14
// 186.388 us; speedup vs baseline: 1.1033x; 1.1033x over previous
//
#include <hip/hip_runtime.h>
#include <hip/hip_bf16.h>

#define NN 50000
#define NE 400000
#define IND 64
#define HID 128
#define H3 384
#define FDIM 960
#define NSEL 4096
#define EPSF 0.3f
#define SLOPEF 0.3f
#define NBK 196            // ceil(NN/256) dst-buckets per relation
#define BCAP 4096          // fixed bucket capacity (mean 2048, sigma 45)
#define EPB 4096           // edges per block in fill
#define NOEDGE 0xFFFFFFFFu
#define NBF 98             // blocks per relation in fill = ceil(NE/EPB)

typedef __attribute__((ext_vector_type(8))) short bfrag;   // 8 bf16 (4 VGPR)
typedef __attribute__((ext_vector_type(4))) float f4;
typedef __attribute__((ext_vector_type(8))) unsigned short us8;

__device__ __forceinline__ float leaky1(float v){ return v>=0.f? v : SLOPEF*v; }
__device__ __forceinline__ float b2f(unsigned short u){
  return __uint_as_float(((unsigned)u)<<16);
}
__device__ __forceinline__ unsigned short f2b(float v){
  __hip_bfloat16 b = __float2bfloat16(v);
  return *(unsigned short*)&b;
}

// ================= kA: bucketed fill (blocks 0..293)  UNION  weight-prep/h-cast =================
__global__ __launch_bounds__(256) void k_fill_prep(
    const int* __restrict__ s0,const int* __restrict__ d0,
    const int* __restrict__ s1,const int* __restrict__ d1,
    const int* __restrict__ s2,const int* __restrict__ d2,
    int* __restrict__ bcnt, unsigned int* __restrict__ pairbuf,
    const float* __restrict__ t1w,
    const float* __restrict__ hw1_0, const float* __restrict__ hw1_1, const float* __restrict__ hw1_2,
    const float* __restrict__ hw2_0, const float* __restrict__ hw2_1, const float* __restrict__ hw2_2,
    const float* __restrict__ t2w, const float* __restrict__ h,
    unsigned short* __restrict__ wt1, unsigned short* __restrict__ w1t,
    unsigned short* __restrict__ w2t, unsigned short* __restrict__ wt2,
    unsigned short* __restrict__ hb)
{
  __shared__ __align__(16) unsigned int lbuf[EPB];   // 16 KB
  __shared__ int hist[256];
  __shared__ int lbase[256];
  __shared__ int lcur[256];
  __shared__ int gbase[NBK];
  __shared__ int wsum[4];
  const int t = threadIdx.x;

  if (blockIdx.x < 3*NBF){
    const int r = blockIdx.x / NBF;
    const int bx = blockIdx.x - r*NBF;
    const int* S = (r==0)?s0:((r==1)?s1:s2);
    const int* D = (r==0)?d0:((r==1)?d1:d2);
    const int e0 = bx*EPB;
    hist[t] = 0; lcur[t] = 0;
    __syncthreads();
    unsigned int pv[16];
    #pragma unroll
    for (int j=0;j<4;j++){
      int e = e0 + (j*256 + t)*4;
      if (e < NE){
        int4 sv = *(const int4*)&S[e];
        int4 dv = *(const int4*)&D[e];
        pv[j*4+0] = ((unsigned)dv.x<<16)|(unsigned)sv.x;
        pv[j*4+1] = ((unsigned)dv.y<<16)|(unsigned)sv.y;
        pv[j*4+2] = ((unsigned)dv.z<<16)|(unsigned)sv.z;
        pv[j*4+3] = ((unsigned)dv.w<<16)|(unsigned)sv.w;
      } else {
        pv[j*4+0]=NOEDGE; pv[j*4+1]=NOEDGE; pv[j*4+2]=NOEDGE; pv[j*4+3]=NOEDGE;
      }
    }
    #pragma unroll
    for (int i=0;i<16;i++){
      if (pv[i] != NOEDGE) atomicAdd(&hist[pv[i]>>24], 1);
    }
    __syncthreads();
    {
      int hv = hist[t];
      int lane = t & 63, wid = t >> 6;
      int x = hv;
      #pragma unroll
      for (int d=1; d<64; d<<=1){ int y=__shfl_up(x,(unsigned)d); if(lane>=d) x+=y; }
      if (lane==63) wsum[wid]=x;
      __syncthreads();
      int wpre = 0;
      if (wid>0) wpre += wsum[0];
      if (wid>1) wpre += wsum[1];
      if (wid>2) wpre += wsum[2];
      lbase[t] = wpre + x - hv;
      if (t < NBK){
        int hh = hist[t];
        gbase[t] = (hh>0) ? atomicAdd(&bcnt[r*NBK+t], hh) : 0;
      }
    }
    __syncthreads();
    #pragma unroll
    for (int i=0;i<16;i++){
      if (pv[i] != NOEDGE){
        int b = (int)(pv[i] >> 24);
        int pos = lbase[b] + atomicAdd(&lcur[b], 1);
        lbuf[pos] = pv[i];
      }
    }
    __syncthreads();
    int tot = min(NE - e0, EPB);
    for (int idx = t; idx < tot; idx += 256){
      unsigned int v = lbuf[idx];
      int b = (int)(v >> 24);
      pairbuf[((size_t)(r*NBK + b))*BCAP + gbase[b] + (idx - lbase[b])] = v;
    }
  } else {
    int g = (blockIdx.x - 3*NBF)*256 + t;
    if (g < 8192){
      wt1[g] = f2b(t1w[g]);
    } else if (g < 57344){
      int e = g - 8192;
      int r = e / 16384, q = e - r*16384;
      int n = q >> 7, k = q & 127;
      const float* W = (r==0)?hw1_0:((r==1)?hw1_1:hw1_2);
      w1t[e] = f2b(W[k*HID + n]);
    } else if (g < 204800){
      int e = g - 57344;
      int r = e / 49152, q = e - r*49152;
      int n = q / H3, k = q - n*H3;
      const float* W = (r==0)?hw2_0:((r==1)?hw2_1:hw2_2);
      w2t[e] = f2b(W[k*HID + n]);
    } else if (g < 266240){
      int e = g - 204800;
      wt2[e] = f2b(t2w[e]);
    } else if (g < 666240){
      int q = g - 266240;
      const float4 a = ((const float4*)h)[q*2];
      const float4 b = ((const float4*)h)[q*2+1];
      us8 o;
      o[0]=f2b(a.x); o[1]=f2b(a.y); o[2]=f2b(a.z); o[3]=f2b(a.w);
      o[4]=f2b(b.x); o[5]=f2b(b.y); o[6]=f2b(b.z); o[7]=f2b(b.w);
      *(us8*)&hb[q*8] = o;
    }
  }
}

// ================= kB: bsort+off+dnv (0..587)  UNION  t1 MFMA (588..1369) =================
__global__ __launch_bounds__(256) void k_sort_t1(
    const unsigned int* __restrict__ pairbuf, const int* __restrict__ bcnt,
    int* __restrict__ off, float* __restrict__ dnv, unsigned short* __restrict__ csrc,
    const unsigned short* __restrict__ Ab, const unsigned short* __restrict__ W,
    const float* __restrict__ bias, unsigned short* __restrict__ Cb)
{
  __shared__ __align__(16) char smem[27648];
  const int t = threadIdx.x;

  if (blockIdx.x < 3*NBK){
    unsigned short* lout = (unsigned short*)smem;            // 8192 B
    int* hist = (int*)(smem + 8192);
    int* excl = (int*)(smem + 9216);
    int* cur  = (int*)(smem + 10240);
    int* red  = (int*)(smem + 11264);
    int* wsum = (int*)(smem + 12288);
    const int r = blockIdx.x / NBK;
    const int b = blockIdx.x - r*NBK;
    const int nb0 = b << 8;
    red[t] = (t < b) ? bcnt[r*NBK + t] : 0;
    hist[t] = 0; cur[t] = 0;
    __syncthreads();
    #pragma unroll
    for (int sdv=128; sdv>0; sdv>>=1){
      if (t < sdv) red[t] += red[t+sdv];
      __syncthreads();
    }
    const int bbase = red[0];
    const int cnt = bcnt[r*NBK + b];
    const unsigned int* pb = pairbuf + ((size_t)(r*NBK + b))*BCAP;
    unsigned int pv[16];
    #pragma unroll
    for (int j=0;j<16;j++){
      int e = j*256 + t;
      pv[j] = (e < cnt) ? pb[e] : NOEDGE;
      if (pv[j] != NOEDGE) atomicAdd(&hist[(int)(pv[j]>>16) - nb0], 1);
    }
    __syncthreads();
    {
      int hv = hist[t];
      int lane = t & 63, wid = t >> 6;
      int x = hv;
      #pragma unroll
      for (int d=1; d<64; d<<=1){ int y=__shfl_up(x,(unsigned)d); if(lane>=d) x+=y; }
      if (lane==63) wsum[wid]=x;
      __syncthreads();
      int wpre = 0;
      if (wid>0) wpre += wsum[0];
      if (wid>1) wpre += wsum[1];
      if (wid>2) wpre += wsum[2];
      excl[t] = wpre + x - hv;
    }
    __syncthreads();
    int nidx = nb0 + t;
    if (nidx < NN){
      off[r*(NN+1) + nidx] = bbase + excl[t];
      int g = hist[t];
      dnv[r*NN + nidx] = (g>0) ? rsqrtf((float)g) : 0.f;
    }
    if (b == NBK-1 && t == 0) off[r*(NN+1) + NN] = bbase + cnt;
    #pragma unroll
    for (int j=0;j<16;j++){
      if (pv[j] != NOEDGE){
        int pn = (int)(pv[j] >> 16) - nb0;
        int slot = atomicAdd(&cur[pn], 1);
        lout[excl[pn] + slot] = (unsigned short)(pv[j] & 0xffffu);
      }
    }
    __syncthreads();
    unsigned short* op = csrc + (size_t)r*NE + bbase;
    for (int idx = t; idx < cnt; idx += 256) op[idx] = lout[idx];
  } else {
    short (*As)[72] = (short(*)[72])smem;                    // 9216 B
    short (*Bs)[72] = (short(*)[72])(smem + 9216);           // 18432 B
    const int bm = (blockIdx.x - 3*NBK)*64;
    for (int q = t; q < 64*8; q += 256){
      int row = q >> 3, c8 = q & 7;
      int grow = bm + row; grow = (grow < NN) ? grow : (NN-1);
      *(us8*)&As[row][c8*8] = *(const us8*)&Ab[(size_t)grow*IND + c8*8];
    }
    for (int q = t; q < 128*8; q += 256){
      int n = q >> 3, c8 = q & 7;
      *(us8*)&Bs[n][c8*8] = *(const us8*)&W[n*IND + c8*8];
    }
    __syncthreads();
    const int wid = t >> 6, lane = t & 63;
    const int wrow = (wid & 1)*32, wcol = (wid >> 1)*64;
    const int fr = lane & 15, fq = lane >> 4;
    f4 acc[2][4];
    #pragma unroll
    for (int mi=0;mi<2;mi++)
      #pragma unroll
      for (int ni=0;ni<4;ni++) acc[mi][ni] = (f4){0.f,0.f,0.f,0.f};
    #pragma unroll
    for (int ks=0; ks<2; ks++){
      int kb = ks*32 + fq*8;
      bfrag a[2], b[4];
      #pragma unroll
      for (int mi=0;mi<2;mi++) a[mi] = *(const bfrag*)&As[wrow + mi*16 + fr][kb];
      #pragma unroll
      for (int ni=0;ni<4;ni++) b[ni] = *(const bfrag*)&Bs[wcol + ni*16 + fr][kb];
      #pragma unroll
      for (int mi=0;mi<2;mi++)
        #pragma unroll
        for (int ni=0;ni<4;ni++)
          acc[mi][ni] = __builtin_amdgcn_mfma_f32_16x16x32_bf16(a[mi], b[ni], acc[mi][ni], 0, 0, 0);
    }
    #pragma unroll
    for (int mi=0;mi<2;mi++){
      int row0 = bm + wrow + mi*16 + fq*4;
      #pragma unroll
      for (int j=0;j<4;j++){
        int row = row0 + j;
        if (row < NN){
          #pragma unroll
          for (int ni=0;ni<4;ni++){
            int col = wcol + ni*16 + fr;
            Cb[(size_t)row*HID + col] = f2b(leaky1(acc[mi][ni][j] + bias[col]));
          }
        }
      }
    }
  }
}

// ---------- batched bf16 MFMA: raw2b[:, r*128..] = leaky(pre1b[r] @ hw1[r]) ----------
__global__ __launch_bounds__(256) void k_mfma128(
    const unsigned short* __restrict__ Abf, const unsigned short* __restrict__ Wt,
    unsigned short* __restrict__ Cb, int M)
{
  __shared__ short As[64][136];
  __shared__ short Bs[128][136];
  const int r = blockIdx.y;
  const unsigned short* Ar = Abf + (size_t)r*M*HID;
  const unsigned short* W  = Wt + (size_t)r*HID*HID;
  const int tid = threadIdx.x;
  const int bm = blockIdx.x*64;

  for (int q = tid; q < 64*16; q += 256){
    int row = q >> 4, c8 = q & 15;
    int grow = bm + row; grow = (grow < M) ? grow : (M-1);
    *(us8*)&As[row][c8*8] = *(const us8*)&Ar[(size_t)grow*HID + c8*8];
  }
  for (int q = tid; q < 128*16; q += 256){
    int n = q >> 4, c8 = q & 15;
    *(us8*)&Bs[n][c8*8] = *(const us8*)&W[n*HID + c8*8];
  }
  __syncthreads();

  const int wid = tid >> 6, lane = tid & 63;
  const int wrow = (wid & 1)*32, wcol = (wid >> 1)*64;
  const int fr = lane & 15, fq = lane >> 4;
  f4 acc[2][4];
  #pragma unroll
  for (int mi=0;mi<2;mi++)
    #pragma unroll
    for (int ni=0;ni<4;ni++) acc[mi][ni] = (f4){0.f,0.f,0.f,0.f};

  #pragma unroll
  for (int ks=0; ks<4; ks++){
    int kb = ks*32 + fq*8;
    bfrag a[2], b[4];
    #pragma unroll
    for (int mi=0;mi<2;mi++) a[mi] = *(const bfrag*)&As[wrow + mi*16 + fr][kb];
    #pragma unroll
    for (int ni=0;ni<4;ni++) b[ni] = *(const bfrag*)&Bs[wcol + ni*16 + fr][kb];
    #pragma unroll
    for (int mi=0;mi<2;mi++)
      #pragma unroll
      for (int ni=0;ni<4;ni++)
        acc[mi][ni] = __builtin_amdgcn_mfma_f32_16x16x32_bf16(a[mi], b[ni], acc[mi][ni], 0, 0, 0);
  }

  const int coff = r*HID;
  #pragma unroll
  for (int mi=0;mi<2;mi++){
    int row0 = bm + wrow + mi*16 + fq*4;
    #pragma unroll
    for (int j=0;j<4;j++){
      int row = row0 + j;
      if (row < M){
        #pragma unroll
        for (int ni=0;ni<4;ni++){
          Cb[(size_t)row*H3 + coff + wcol + ni*16 + fr] = f2b(leaky1(acc[mi][ni][j]));
        }
      }
    }
  }
}

// ================= kH: hw2 MFMA (0..383)  UNION  nf fill =================
__global__ __launch_bounds__(256) void k_hw2_nf(
    const unsigned short* __restrict__ Abf, const unsigned short* __restrict__ Wt,
    const unsigned short* __restrict__ hb, const unsigned short* __restrict__ raw1b,
    const unsigned short* __restrict__ raw2b, const int* __restrict__ nodes,
    unsigned short* __restrict__ nfb)
{
  __shared__ __align__(16) char smem[23040];
  const int t = threadIdx.x;
  if (blockIdx.x < 3*128){
    short (*As)[72] = (short(*)[72])smem;
    short (*Bs)[72] = (short(*)[72])(smem + 4608);
    const int r = blockIdx.x / 128;
    const int bm = (blockIdx.x - r*128)*32;
    const unsigned short* Ar = Abf + (size_t)r*NSEL*H3;
    const unsigned short* W  = Wt + (size_t)r*HID*H3;
    const int wid = t >> 6, lane = t & 63;
    const int fr = lane & 15, fq = lane >> 4;
    f4 acc[2][2];
    #pragma unroll
    for (int mi=0;mi<2;mi++)
      #pragma unroll
      for (int ni=0;ni<2;ni++) acc[mi][ni] = (f4){0.f,0.f,0.f,0.f};
    for (int kc=0; kc<6; kc++){
      for (int q = t; q < 32*8; q += 256){
        int row = q >> 3, c8 = q & 7;
        *(us8*)&As[row][c8*8] = *(const us8*)&Ar[(size_t)(bm+row)*H3 + kc*64 + c8*8];
      }
      for (int q = t; q < 128*8; q += 256){
        int n = q >> 3, c8 = q & 7;
        *(us8*)&Bs[n][c8*8] = *(const us8*)&W[(size_t)n*H3 + kc*64 + c8*8];
      }
      __syncthreads();
      #pragma unroll
      for (int ks=0; ks<2; ks++){
        int kb = ks*32 + fq*8;
        bfrag a[2], b[2];
        #pragma unroll
        for (int mi=0;mi<2;mi++) a[mi] = *(const bfrag*)&As[mi*16 + fr][kb];
        #pragma unroll
        for (int ni=0;ni<2;ni++) b[ni] = *(const bfrag*)&Bs[wid*32 + ni*16 + fr][kb];
        #pragma unroll
        for (int mi=0;mi<2;mi++)
          #pragma unroll
          for (int ni=0;ni<2;ni++)
            acc[mi][ni] = __builtin_amdgcn_mfma_f32_16x16x32_bf16(a[mi], b[ni], acc[mi][ni], 0, 0, 0);
      }
      __syncthreads();
    }
    #pragma unroll
    for (int mi=0;mi<2;mi++){
      int row0 = bm + mi*16 + fq*4;
      #pragma unroll
      for (int j=0;j<4;j++){
        int i = row0 + j;
        #pragma unroll
        for (int ni=0;ni<2;ni++){
          int col = wid*32 + ni*16 + fr;
          nfb[(size_t)i*FDIM + r*HID + col] = f2b(leaky1(acc[mi][ni][j]));
        }
      }
    }
  } else {
    int g = (blockIdx.x - 3*128)*256 + t;
    if (g < NSEL*72){
      int i = g/72, c = g - i*72;
      int n = nodes[i];
      us8 v; int col;
      if (c < 8)       { v = *(const us8*)&hb[(size_t)n*IND + c*8];           col = 384 + c*8; }
      else if (c < 24) { int q=c-8;  v = *(const us8*)&raw1b[(size_t)n*HID + q*8]; col = 448 + q*8; }
      else             { int q=c-24; v = *(const us8*)&raw2b[(size_t)n*H3  + q*8]; col = 576 + q*8; }
      *(us8*)&nfb[(size_t)i*FDIM + col] = v;
    }
  }
}

// ================= kT2F: t2 MFMA (K=960) + fused bias/leaky/t3 epilogue =================
__global__ __launch_bounds__(256) void k_t2_final(
    const unsigned short* __restrict__ Abf, const unsigned short* __restrict__ W,
    const float* __restrict__ t2b, const float* __restrict__ t3w,
    const float* __restrict__ t3b, float* __restrict__ outp)
{
  __shared__ __align__(16) char smem[13824];
  short (*As)[72] = (short(*)[72])smem;
  short (*Bs)[72] = (short(*)[72])(smem + 4608);
  float (*sb)[64] = (float(*)[64])smem;
  const int t = threadIdx.x;
  const int bm = blockIdx.x*32;
  const int wid = t >> 6, lane = t & 63;
  const int fr = lane & 15, fq = lane >> 4;
  f4 acc[2];
  acc[0] = (f4){0.f,0.f,0.f,0.f};
  acc[1] = (f4){0.f,0.f,0.f,0.f};

  for (int kc=0; kc<15; kc++){
    for (int q = t; q < 32*8; q += 256){
      int row = q >> 3, c8 = q & 7;
      *(us8*)&As[row][c8*8] = *(const us8*)&Abf[(size_t)(bm+row)*FDIM + kc*64 + c8*8];
    }
    for (int q = t; q < 64*8; q += 256){
      int n = q >> 3, c8 = q & 7;
      *(us8*)&Bs[n][c8*8] = *(const us8*)&W[(size_t)n*FDIM + kc*64 + c8*8];
    }
    __syncthreads();
    #pragma unroll
    for (int ks=0; ks<2; ks++){
      int kb = ks*32 + fq*8;
      bfrag a[2], b;
      a[0] = *(const bfrag*)&As[fr][kb];
      a[1] = *(const bfrag*)&As[16 + fr][kb];
      b = *(const bfrag*)&Bs[wid*16 + fr][kb];
      acc[0] = __builtin_amdgcn_mfma_f32_16x16x32_bf16(a[0], b, acc[0], 0, 0, 0);
      acc[1] = __builtin_amdgcn_mfma_f32_16x16x32_bf16(a[1], b, acc[1], 0, 0, 0);
    }
    __syncthreads();
  }

  #pragma unroll
  for (int mi=0;mi<2;mi++){
    int rloc = mi*16 + fq*4;
    #pragma unroll
    for (int j=0;j<4;j++){
      sb[rloc+j][wid*16 + fr] = acc[mi][j];
    }
  }
  __syncthreads();
  for (int rr = wid*8; rr < wid*8+8; rr++){
    float v = leaky1(sb[rr][lane] + t2b[lane]);
    float a0 = v*t3w[lane], a1 = v*t3w[64+lane];
    #pragma unroll
    for (int sft=32;sft>0;sft>>=1){
      a0 += __shfl_down(a0,(unsigned)sft);
      a1 += __shfl_down(a1,(unsigned)sft);
    }
    if (lane==0){
      int w = bm + rr;
      outp[2*w+0] = a0 + t3b[0];
      outp[2*w+1] = a1 + t3b[1];
    }
  }
}

// ---------- per-node gate scores: group(16)-per-node, us8 loads ----------
template<int D>
__global__ __launch_bounds__(256) void k_scores_g(const unsigned short* __restrict__ X,
    const float* __restrict__ g0, const float* __restrict__ g1, const float* __restrict__ g2,
    float* __restrict__ sd, float* __restrict__ ss){
  const int tid = threadIdx.x;
  const int p = tid & 15;
  const int n = blockIdx.x*16 + (tid >> 4);
  const unsigned short* x = X + (size_t)n*D;
  float a0=0,a1=0,a2=0,a3=0,a4=0,a5=0;
  #pragma unroll
  for (int it=0; it<D/128; it++){
    int k = it*128 + p*8;
    us8 u = *(const us8*)&x[k];
    #pragma unroll
    for (int e=0;e<8;e++){
      float v = b2f(u[e]);
      a0 = fmaf(v, g0[k+e],   a0);  a1 = fmaf(v, g0[D+k+e], a1);
      a2 = fmaf(v, g1[k+e],   a2);  a3 = fmaf(v, g1[D+k+e], a3);
      a4 = fmaf(v, g2[k+e],   a4);  a5 = fmaf(v, g2[D+k+e], a5);
    }
  }
  #pragma unroll
  for (int s=8;s>0;s>>=1){
    a0 += __shfl_xor(a0,(unsigned)s); a1 += __shfl_xor(a1,(unsigned)s);
    a2 += __shfl_xor(a2,(unsigned)s); a3 += __shfl_xor(a3,(unsigned)s);
    a4 += __shfl_xor(a4,(unsigned)s); a5 += __shfl_xor(a5,(unsigned)s);
  }
  if (p==0){
    sd[0*NN+n]=a0; ss[0*NN+n]=a1;
    sd[1*NN+n]=a2; ss[1*NN+n]=a3;
    sd[2*NN+n]=a4; ss[2*NN+n]=a5;
  }
}

// ---------- layer-1 aggregation: group(16)-per-node, 3 rels fused, 1-ahead pipeline ----------
__global__ __launch_bounds__(256) void k_gather_f3z(
    const unsigned short* __restrict__ Xb,
    const int* __restrict__ off, const unsigned short* __restrict__ csrc,
    const float* __restrict__ sd, const float* __restrict__ ss,
    const float* __restrict__ dnv,
    const float* __restrict__ gb0, const float* __restrict__ gb1, const float* __restrict__ gb2,
    unsigned short* __restrict__ outp){
  const int tid = threadIdx.x;
  const int lane = tid & 63;
  const int wg = lane >> 4;
  const int p  = lane & 15;
  const int n = blockIdx.x*16 + (tid >> 4);
  us8 rv = *(const us8*)&Xb[(size_t)n*HID + p*8];
  int p0a[3], p1a[3];
  #pragma unroll
  for (int r=0;r<3;r++){
    p0a[r] = off[r*(NN+1) + n];
    p1a[r] = off[r*(NN+1) + n + 1];
  }
  float resid[8];
  #pragma unroll
  for (int i=0;i<8;i++) resid[i] = EPSF * b2f(rv[i]);

  for (int r=0;r<3;r++){
    const unsigned short* csr = csrc + (size_t)r*NE;
    const float* ssr = ss + r*NN;
    const float* dnr = dnv + r*NN;
    float gbv = ((r==0)?gb0:((r==1)?gb1:gb2))[0];
    float sd_n = sd[r*NN + n], dn_n = dnr[n];
    float acc[8];
    #pragma unroll
    for (int i=0;i<8;i++) acc[i] = resid[i];
    int p0 = p0a[r], p1 = p1a[r];
    for (int pc=p0; pc<p1; pc+=16){
      int m = min(16, p1-pc);
      int s = 0; float c = 0.f;
      if (p < m){
        s = csr[pc+p];
        c = tanhf(sd_n + ssr[s] + gbv) * dn_n * dnr[s];
      }
      int   sj = __shfl(s, wg*16);
      float cj = __shfl(c, wg*16);
      us8 v = *(const us8*)&Xb[(size_t)sj*HID + p*8];
      for (int j=1;j<=m;j++){
        us8 vn; float cn = 0.f;
        if (j < m){
          int sn = __shfl(s, wg*16+j);
          cn = __shfl(c, wg*16+j);
          vn = *(const us8*)&Xb[(size_t)sn*HID + p*8];
        }
        #pragma unroll
        for (int i=0;i<8;i++) acc[i] = fmaf(cj, b2f(v[i]), acc[i]);
        v = vn; cj = cn;
      }
    }
    us8 o;
    #pragma unroll
    for (int i=0;i<8;i++) o[i] = f2b(acc[i]);
    *(us8*)&outp[((size_t)r*NN + n)*HID + p*8] = o;
  }
}

// ---------- layer-2 selected aggregation: group-per-node, D=384, 1-ahead pipeline ----------
__global__ __launch_bounds__(256) void k_gather_sel3w2(const unsigned short* __restrict__ Xb,
    const int* __restrict__ nodes,
    const int* __restrict__ off, const unsigned short* __restrict__ csrc,
    const float* __restrict__ sd, const float* __restrict__ ss,
    const float* __restrict__ dnv,
    const float* __restrict__ gb0, const float* __restrict__ gb1, const float* __restrict__ gb2,
    unsigned short* __restrict__ outp){
  const int tid = threadIdx.x;
  const int lane = tid & 63;
  const int wg = lane >> 4;
  const int p  = lane & 15;
  const int i = blockIdx.x*16 + (tid >> 4);
  const int r = blockIdx.y;
  const int n = nodes[i];
  const int* offr = off + r*(NN+1);
  const unsigned short* csr = csrc + (size_t)r*NE;
  const float* ssr = ss + r*NN;
  const float* dnr = dnv + r*NN;
  float gbv = ((r==0)?gb0:((r==1)?gb1:gb2))[0];
  float sd_n = sd[r*NN + n], dn_n = dnr[n];
  float acc[3][8];
  #pragma unroll
  for (int cc=0;cc<3;cc++)
    #pragma unroll
    for (int q=0;q<8;q++) acc[cc][q]=0.f;
  int p0 = offr[n], p1 = offr[n+1];
  for (int pc=p0; pc<p1; pc+=16){
    int m = min(16, p1-pc);
    int s = 0; float c = 0.f;
    if (p < m){
      s = csr[pc+p];
      c = tanhf(sd_n + ssr[s] + gbv) * dn_n * dnr[s];
    }
    int   sj = __shfl(s, wg*16);
    float cj = __shfl(c, wg*16);
    const unsigned short* row = &Xb[(size_t)sj*H3];
    us8 v0 = *(const us8*)&row[0*HID + p*8];
    us8 v1 = *(const us8*)&row[1*HID + p*8];
    us8 v2 = *(const us8*)&row[2*HID + p*8];
    for (int j=1;j<=m;j++){
      us8 n0, n1, n2; float cn = 0.f;
      if (j < m){
        int sn = __shfl(s, wg*16+j);
        cn = __shfl(c, wg*16+j);
        const unsigned short* rw = &Xb[(size_t)sn*H3];
        n0 = *(const us8*)&rw[0*HID + p*8];
        n1 = *(const us8*)&rw[1*HID + p*8];
        n2 = *(const us8*)&rw[2*HID + p*8];
      }
      #pragma unroll
      for (int q=0;q<8;q++){
        acc[0][q] = fmaf(cj, b2f(v0[q]), acc[0][q]);
        acc[1][q] = fmaf(cj, b2f(v1[q]), acc[1][q]);
        acc[2][q] = fmaf(cj, b2f(v2[q]), acc[2][q]);
      }
      v0 = n0; v1 = n1; v2 = n2; cj = cn;
    }
  }
  const unsigned short* xrow = &Xb[(size_t)n*H3];
  unsigned short* orow = &outp[((size_t)r*NSEL + i)*H3];
  #pragma unroll
  for (int cc=0;cc<3;cc++){
    us8 v = *(const us8*)&xrow[cc*HID + p*8];
    us8 o;
    #pragma unroll
    for (int q=0;q<8;q++) o[q] = f2b(fmaf(EPSF, b2f(v[q]), acc[cc][q]));
    *(us8*)&orow[cc*HID + p*8] = o;
  }
}

extern "C" void kernel_launch(void* const* d_in, const int* in_sizes, int n_in,
                              void* d_out, int out_size, void* d_ws, size_t ws_size,
                              hipStream_t stream){
  if (n_in < 32) return;
  const float* h = (const float*)d_in[0];
  const int* src[3] = {(const int*)d_in[1], (const int*)d_in[3], (const int*)d_in[5]};
  const int* dst[3] = {(const int*)d_in[2], (const int*)d_in[4], (const int*)d_in[6]};
  const int* nodes = (const int*)d_in[7];
  const float* t1w = (const float*)d_in[8];
  const float* t1b = (const float*)d_in[9];

  bool dictOrder = (in_sizes[12] == 768);
  const float *g1w[3],*g1b[3],*g2w[3],*g2b[3],*hw1[3],*hw2[3];
  for (int r=0;r<3;r++){
    if (dictOrder){
      int base = 10 + r*6;
      g1w[r]=(const float*)d_in[base+0]; g1b[r]=(const float*)d_in[base+1];
      g2w[r]=(const float*)d_in[base+2]; g2b[r]=(const float*)d_in[base+3];
      hw1[r]=(const float*)d_in[base+4]; hw2[r]=(const float*)d_in[base+5];
    } else {
      g1w[r]=(const float*)d_in[10+2*r]; g1b[r]=(const float*)d_in[11+2*r];
      g2w[r]=(const float*)d_in[16+2*r]; g2b[r]=(const float*)d_in[17+2*r];
      hw1[r]=(const float*)d_in[22+r];   hw2[r]=(const float*)d_in[25+r];
    }
  }
  const float* t2w = (const float*)d_in[28];
  const float* t2b = (const float*)d_in[29];
  const float* t3w = (const float*)d_in[30];
  const float* t3b = (const float*)d_in[31];
  float* outp = (float*)d_out;

  // workspace carve (~115 MB)
  char* w = (char*)d_ws;
  auto carve = [&](size_t bytes)->void*{
    void* p = (void*)w;
    w += ((bytes + 255) & ~size_t(255));
    return p;
  };
  int*   bcnt = (int*)  carve((size_t)1024*4);
  int*   off  = (int*)  carve((size_t)3*(NN+1)*4);
  float* dnv  = (float*)carve((size_t)3*NN*4);
  unsigned short* csrc = (unsigned short*)carve((size_t)3*NE*2);
  float* sd1  = (float*)carve((size_t)3*NN*4);
  float* ss1  = (float*)carve((size_t)3*NN*4);
  float* sd2  = (float*)carve((size_t)3*NN*4);
  float* ss2  = (float*)carve((size_t)3*NN*4);
  unsigned short* wt1 = (unsigned short*)carve((size_t)HID*IND*2);
  unsigned short* w1t = (unsigned short*)carve((size_t)3*HID*HID*2);
  unsigned short* w2t = (unsigned short*)carve((size_t)3*HID*H3*2);
  unsigned short* wt2 = (unsigned short*)carve((size_t)64*FDIM*2);
  unsigned short* hb  = (unsigned short*)carve((size_t)NN*IND*2);
  unsigned short* raw1b = (unsigned short*)carve((size_t)NN*HID*2);
  unsigned short* raw2b = (unsigned short*)carve((size_t)NN*H3*2);
  // union region (38.4MB): pairbuf u32 [3*NBK*BCAP] | pre1b [3][NN][HID] | pre2b [3][NSEL][H3]
  size_t ubytes = (size_t)3*NN*HID*2;
  float* ureg = (float*)carve(ubytes);
  unsigned int* pairbuf = (unsigned int*)ureg;
  unsigned short* pre1b = (unsigned short*)ureg;
  unsigned short* pre2b = (unsigned short*)ureg;
  unsigned short* nfb = (unsigned short*)carve((size_t)NSEL*FDIM*2);

  hipMemsetAsync(bcnt, 0, (size_t)1024*4, stream);
  // kA: fill + weight-prep (independent, one dispatch)
  k_fill_prep<<<3*NBF + 2603, 256, 0, stream>>>(
      src[0],dst[0],src[1],dst[1],src[2],dst[2], bcnt, pairbuf,
      t1w, hw1[0], hw1[1], hw1[2], hw2[0], hw2[1], hw2[2], t2w, h,
      wt1, w1t, w2t, wt2, hb);
  // kB: bucket-sort/off/dnv + t1 MFMA (both depend only on kA)
  k_sort_t1<<<3*NBK + (NN+63)/64, 256, 0, stream>>>(
      pairbuf, bcnt, off, dnv, csrc, hb, wt1, t1b, raw1b);

  k_scores_g<HID><<<NN/16, 256, 0, stream>>>(raw1b, g1w[0], g1w[1], g1w[2], sd1, ss1);

  k_gather_f3z<<<NN/16, 256, 0, stream>>>(raw1b, off, csrc,
      sd1, ss1, dnv, g1b[0], g1b[1], g1b[2], pre1b);
  k_mfma128<<<dim3((NN+63)/64, 3), 256, 0, stream>>>(pre1b, w1t, raw2b, NN);

  k_scores_g<H3><<<NN/16, 256, 0, stream>>>(raw2b, g2w[0], g2w[1], g2w[2], sd2, ss2);

  k_gather_sel3w2<<<dim3(NSEL/16, 3), 256, 0, stream>>>(raw2b, nodes, off, csrc,
      sd2, ss2, dnv, g2b[0], g2b[1], g2b[2], pre2b);

  // kH: hw2 MFMA + nf fill (one dispatch)
  k_hw2_nf<<<3*128 + (NSEL*72+255)/256, 256, 0, stream>>>(
      pre2b, w2t, hb, raw1b, raw2b, nodes, nfb);

  // kT2F: t2 MFMA with fused bias/leaky/t3 epilogue
  k_t2_final<<<NSEL/32, 256, 0, stream>>>(nfb, wt2, t2b, t3w, t3b, outp);
}